// Round 10
// baseline (65.629 us; speedup 1.0000x reference)
//
#include <hip/hip_runtime.h>

// Sliding-window min (STL Always_[16,64]):
//   out[t][b] = min_{j=15..63} xpad[t-j][b],   xpad[s<0] = 1e6
// R10: DRAM-locality via block geometry. All first-order knobs are null at an
// invariant ~56us (width R2/R6/R9, occ R3/R7, amp R3 vs R7, nt R4, LDS store
// transpose R9). Theory: with 256-thread blocks, each CU interleaves ~8
// scattered 16KB-strided walks touching 256B/row-visit -> DRAM row-buffer
// thrash caps HBM at ~4.2 TB/s (copy ubench: contiguous waves, 6.3 TB/s).
// Fix: 1024-thread blocks -> 4KB contiguous per row-visit, 2 resident
// blocks/CU (not 8). C_TILE=64 keeps the streaming cascade at VGPR ~64 ->
// 2 blocks x 16 waves = full 32 waves/CU.

#define T_DIM 8192
#define B_DIM 4096
#define C_TILE 64               // outputs per thread along T
#define ALEN (C_TILE + 48)      // inputs per thread (window width 49)
#define LARGE_VAL 1e6f

__global__ __launch_bounds__(1024)
void Temporal_Operator_kernel(const float* __restrict__ x,
                              float* __restrict__ out) {
    const int b  = blockIdx.x * blockDim.x + threadIdx.x;   // column
    const int t0 = blockIdx.y * C_TILE;                     // output tile start
    const long base = (long)t0 - 63;                        // first input row

    // Load inputs (negative rows -> LARGE; wave-uniform predicate, y-tile 0).
    float arr[ALEN];
    #pragma unroll
    for (int i = 0; i < ALEN; ++i) {
        long s = base + i;
        arr[i] = (s >= 0) ? x[s * B_DIM + b] : LARGE_VAL;
    }

    // Log-doubling forward window mins, in place:
    // after pass k, arr[i] = min(x[i .. i+k-1]) over the valid range.
    #pragma unroll
    for (int i = 0; i < ALEN - 1; ++i)  arr[i] = fminf(arr[i], arr[i + 1]);   // w2
    #pragma unroll
    for (int i = 0; i < ALEN - 3; ++i)  arr[i] = fminf(arr[i], arr[i + 2]);   // w4
    #pragma unroll
    for (int i = 0; i < ALEN - 7; ++i)  arr[i] = fminf(arr[i], arr[i + 4]);   // w8
    #pragma unroll
    for (int i = 0; i < ALEN - 15; ++i) arr[i] = fminf(arr[i], arr[i + 8]);   // w16
    #pragma unroll
    for (int i = 0; i < ALEN - 31; ++i) arr[i] = fminf(arr[i], arr[i + 16]);  // w32

    // w49[c] = min(w32[c], w32[c+17]) covers [c, c+48]; stream past caches.
    #pragma unroll
    for (int c = 0; c < C_TILE; ++c) {
        __builtin_nontemporal_store(fminf(arr[c], arr[c + 17]),
                                    &out[(long)(t0 + c) * B_DIM + b]);
    }
}

extern "C" void kernel_launch(void* const* d_in, const int* in_sizes, int n_in,
                              void* d_out, int out_size, void* d_ws, size_t ws_size,
                              hipStream_t stream) {
    const float* x = (const float*)d_in[0];
    float* out = (float*)d_out;

    dim3 block(1024, 1, 1);
    dim3 grid(B_DIM / 1024, T_DIM / C_TILE, 1);   // 4 x 128 blocks
    Temporal_Operator_kernel<<<grid, block, 0, stream>>>(x, out);
}

// Round 11
// 54.891 us; speedup vs baseline: 1.1956x; 1.1956x over previous
//
#include <hip/hip_runtime.h>

// Sliding-window min (STL Always_[16,64]):
//   out[t][b] = min_{j=15..63} xpad[t-j][b],   xpad[s<0] = 1e6
// R11: HBM channel phase-lock test. Row stride 16KB = 64 x 256B granules; if
// channels interleave at 256B over 128 channels, each row hits only HALF the
// channels (parity-selected). All blocks walk rows ascending in lockstep ->
// at any instant only half the channels are active -> ~4 TB/s cap. Matches
// the R1-R10 invariant (3.9-4.3 TB/s sustained, all knobs null).
// Fix: odd-y blocks walk their rows DESCENDING (loads + stores), putting them
// on the opposite row parity -> both channel halves engaged simultaneously.
// Everything else = R7 (scalar, C_TILE=64, nt stores, 256-thread blocks).

#define T_DIM 8192
#define B_DIM 4096
#define C_TILE 64               // outputs per thread along T
#define ALEN (C_TILE + 48)      // inputs per thread (window width 49)
#define LARGE_VAL 1e6f

__global__ __launch_bounds__(256)
void Temporal_Operator_kernel(const float* __restrict__ x,
                              float* __restrict__ out) {
    const int b  = blockIdx.x * blockDim.x + threadIdx.x;   // column
    const int t0 = blockIdx.y * C_TILE;                     // output tile start
    const long base = (long)t0 - 63;                        // first input row
    const bool rev = (blockIdx.y & 1);                      // block-uniform

    // Load inputs (negative rows -> LARGE; wave-uniform predicate, y-tile 0).
    // Two fully-unrolled branches keep arr[] indices static (no scratch);
    // odd-y blocks issue loads in descending row order.
    float arr[ALEN];
    if (!rev) {
        #pragma unroll
        for (int i = 0; i < ALEN; ++i) {
            long s = base + i;
            arr[i] = (s >= 0) ? x[s * B_DIM + b] : LARGE_VAL;
        }
    } else {
        #pragma unroll
        for (int i = ALEN - 1; i >= 0; --i) {
            long s = base + i;
            arr[i] = (s >= 0) ? x[s * B_DIM + b] : LARGE_VAL;
        }
    }

    // Log-doubling forward window mins, in place (order-independent dataflow).
    #pragma unroll
    for (int i = 0; i < ALEN - 1; ++i)  arr[i] = fminf(arr[i], arr[i + 1]);   // w2
    #pragma unroll
    for (int i = 0; i < ALEN - 3; ++i)  arr[i] = fminf(arr[i], arr[i + 2]);   // w4
    #pragma unroll
    for (int i = 0; i < ALEN - 7; ++i)  arr[i] = fminf(arr[i], arr[i + 4]);   // w8
    #pragma unroll
    for (int i = 0; i < ALEN - 15; ++i) arr[i] = fminf(arr[i], arr[i + 8]);   // w16
    #pragma unroll
    for (int i = 0; i < ALEN - 31; ++i) arr[i] = fminf(arr[i], arr[i + 16]);  // w32

    // w49[c] = min(w32[c], w32[c+17]) covers [c, c+48]; stream past caches.
    // Store order matches each block's walk direction.
    if (!rev) {
        #pragma unroll
        for (int c = 0; c < C_TILE; ++c) {
            __builtin_nontemporal_store(fminf(arr[c], arr[c + 17]),
                                        &out[(long)(t0 + c) * B_DIM + b]);
        }
    } else {
        #pragma unroll
        for (int c = C_TILE - 1; c >= 0; --c) {
            __builtin_nontemporal_store(fminf(arr[c], arr[c + 17]),
                                        &out[(long)(t0 + c) * B_DIM + b]);
        }
    }
}

extern "C" void kernel_launch(void* const* d_in, const int* in_sizes, int n_in,
                              void* d_out, int out_size, void* d_ws, size_t ws_size,
                              hipStream_t stream) {
    const float* x = (const float*)d_in[0];
    float* out = (float*)d_out;

    dim3 block(256, 1, 1);
    dim3 grid(B_DIM / 256, T_DIM / C_TILE, 1);   // 16 x 128 blocks
    Temporal_Operator_kernel<<<grid, block, 0, stream>>>(x, out);
}